// Round 5
// baseline (484.041 us; speedup 1.0000x reference)
//
#include <hip/hip_runtime.h>
#include <math.h>

#define H      128
#define LNUM   5
#define ONUM   5
#define BATCH  16
#define NPTS   50000
#define TP     64       // points per trunk block (2 waves)
#define XROW   152      // halfs per xs row: 128+24 pad; stride 76 words == 12 mod 32 -> 2-way max

#define K2LOG2E 2.8853900817779268f   // 2*log2(e): tanh arg -> exp2 arg

typedef _Float16      half8    __attribute__((ext_vector_type(8)));
typedef float         floatx4  __attribute__((ext_vector_type(4)));
typedef unsigned int  uint2v   __attribute__((ext_vector_type(2)));
typedef unsigned int  uint4v   __attribute__((ext_vector_type(4)));
typedef unsigned short ushort8_t __attribute__((ext_vector_type(8)));

// LDS-only barrier: lgkmcnt drain + s_barrier. Cross-wave hazards here are all LDS;
// leaves global (weight) loads in flight across the barrier (no vmcnt(0) stall).
#define BAR() asm volatile("s_waitcnt lgkmcnt(0)\ns_barrier" ::: "memory")

static __device__ __forceinline__ unsigned short f2h(float f) {
    _Float16 h = (_Float16)f;                       // v_cvt_f16_f32 (RNE)
    return __builtin_bit_cast(unsigned short, h);
}

// ============ branch MLP: one block per batch; outputs S (cumsum), ZL ============
__global__ __launch_bounds__(256)
void branch_kernel(const float* __restrict__ params,
                   const float* __restrict__ bW0, const float* __restrict__ bb0,
                   const float* __restrict__ bWh, const float* __restrict__ bbh,
                   const float* __restrict__ balpha,
                   const float* __restrict__ bWf, const float* __restrict__ bbf,
                   float* __restrict__ Sws, unsigned short* __restrict__ ZLws) {
    int b = blockIdx.x, t = threadIdx.x;
    __shared__ float hbuf[H];
    __shared__ float pbuf[8];
    if (t < 8) pbuf[t] = params[b * 8 + t];
    __syncthreads();

    float scum = 0.0f;
    if (t < H) {
        float acc = bb0[t];
        for (int k = 0; k < 8; ++k) acc += pbuf[k] * bW0[k * H + t];
        float h = balpha[t] * tanhf(acc);
        hbuf[t] = h;
        scum = h;
        Sws[(b * LNUM + 0) * H + t] = scum;
    }
    for (int i = 1; i < LNUM; ++i) {
        __syncthreads();
        float hn = 0.0f;
        if (t < H) {
            const float* Wl = bWh + (i - 1) * H * H;
            float a2 = bbh[(i - 1) * H + t];
            for (int k = 0; k < H; ++k) a2 += hbuf[k] * Wl[k * H + t];
            hn = balpha[i * H + t] * tanhf(a2);
        }
        __syncthreads();
        if (t < H) {
            hbuf[t] = hn;
            scum += hn;
            Sws[(b * LNUM + i) * H + t] = scum;
        }
    }
    __syncthreads();
    // ZL[b][o][h], o=5..15 zero rows
    for (int idx = t; idx < 16 * H; idx += 256) {
        int o = idx >> 7, hh = idx & 127;
        float z = 0.0f;
        if (o < ONUM) {
            z = bbf[o * H + hh];
            for (int k = 0; k < H; ++k) z += hbuf[k] * bWf[k * (H * ONUM) + o * H + hh];
        }
        ZLws[b * 16 * H + idx] = f2h(z);
    }
}

// ============ massively-parallel weight fold: grid (16, 6) ============
// whs[b][l-1][f][k] = 2log2e*S_l[f]*Wh[l-1][k][f];  w0s similar (K padded to 32); wft plain.
__global__ __launch_bounds__(256)
void fold_kernel(const float* __restrict__ tW0, const float* __restrict__ tb0,
                 const float* __restrict__ tWh, const float* __restrict__ tbh,
                 const float* __restrict__ tWf, const float* __restrict__ Sws,
                 unsigned short* __restrict__ w0s, unsigned short* __restrict__ whs,
                 unsigned short* __restrict__ wft, float* __restrict__ binit) {
    int b = blockIdx.x, l = blockIdx.y, t = threadIdx.x;
    if (l == 5) {
        if (b == 0) {
            for (int i = t; i < H * H; i += 256) {
                int k = i >> 7, f = i & 127;          // src coalesced
                wft[f * H + k] = f2h(tWf[i]);
            }
        }
        return;
    }
    const float* Srow = Sws + (b * LNUM + l) * H;
    if (l == 0) {
        for (int i = t; i < H * 32; i += 256) {
            int f = i >> 5, k = i & 31;
            float v = (k < 3) ? K2LOG2E * Srow[f] * tW0[k * H + f] : 0.0f;
            w0s[b * H * 32 + i] = f2h(v);
        }
        if (t < H) binit[(b * LNUM + 0) * H + t] = K2LOG2E * Srow[t] * tb0[t];
    } else {
        const float* Wsrc = tWh + (l - 1) * H * H;
        unsigned short* dst = whs + (b * 4 + (l - 1)) * H * H;
        for (int i = t; i < H * H; i += 256) {
            int k = i >> 7, f = i & 127;              // src coalesced
            dst[f * H + k] = f2h(K2LOG2E * Srow[f] * Wsrc[i]);
        }
        if (t < H) binit[(b * LNUM + l) * H + t] = K2LOG2E * Srow[t] * tbh[(l - 1) * H + t];
    }
}

// ============ trunk: 64 points/block (2 waves), fp16 MFMA, feature-major D ============
__global__ __launch_bounds__(128, 4)
void trunk_kernel(const float* __restrict__ coords,
                  const float* __restrict__ talpha, const float* __restrict__ tbf,
                  const unsigned short* __restrict__ wft,
                  const unsigned short* __restrict__ w0s,
                  const unsigned short* __restrict__ whs,
                  const float* __restrict__ binit,
                  const unsigned short* __restrict__ ZLws,
                  float* __restrict__ out) {
    const int b    = blockIdx.y;
    const int n0   = blockIdx.x * TP;
    const int tid  = threadIdx.x;
    const int lane = tid & 63;
    const int w    = tid >> 6;        // wave 0/1
    const int q    = lane >> 4;       // quad 0..3
    const int c    = lane & 15;
    const int mh   = w * 64;          // wave's feature half (M); both waves cover all 64 points

    __shared__ unsigned short xs[TP * XROW];   // 19456 B -> 8 blocks/CU

    // ---- stage coords into xs[p][0..31] (fp16, zero-padded K) ----
    int valid = NPTS - n0; if (valid > TP) valid = TP;
    {
        int p = tid >> 1, hh = tid & 1;
        if (hh == 0) {
            float c0 = 0.f, c1 = 0.f, c2 = 0.f;
            if (p < valid) {
                const float* cp = coords + ((size_t)b * NPTS + n0 + p) * 3;
                c0 = cp[0]; c1 = cp[1]; c2 = cp[2];
            }
            uint4v z;
            z.x = __builtin_bit_cast(unsigned int, __builtin_amdgcn_cvt_pkrtz(c0, c1));
            z.y = __builtin_bit_cast(unsigned int, __builtin_amdgcn_cvt_pkrtz(c2, 0.0f));
            z.z = 0; z.w = 0;
            *(uint4v*)&xs[p * XROW + 0] = z;                 // k 0..7
            uint4v zz = {0, 0, 0, 0};
            *(uint4v*)&xs[p * XROW + 8] = zz;                // k 8..15
        } else {
            uint4v zz = {0, 0, 0, 0};
            *(uint4v*)&xs[p * XROW + 16] = zz;               // k 16..31
            *(uint4v*)&xs[p * XROW + 24] = zz;
        }
    }
    BAR();

    floatx4 acc[4][4];
    half8 af0[4];                                   // cross-barrier s=0 A-frag prefetch

    // ================= layer 0: coords (K=32, folded W0) =================
    #pragma unroll
    for (int mt = 0; mt < 4; ++mt)
        #pragma unroll
        for (int nt = 0; nt < 4; ++nt)
            acc[mt][nt] = (floatx4){0.f, 0.f, 0.f, 0.f};
    {
        const unsigned short* w0b = w0s + b * H * 32;
        half8 af[4], bfr[4];
        #pragma unroll
        for (int mt = 0; mt < 4; ++mt)
            af[mt] = __builtin_bit_cast(half8,
                *(const ushort8_t*)&w0b[(mh + mt * 16 + c) * 32 + q * 8]);
        #pragma unroll
        for (int nt = 0; nt < 4; ++nt)
            bfr[nt] = __builtin_bit_cast(half8,
                *(const ushort8_t*)&xs[(nt * 16 + c) * XROW + q * 8]);
        #pragma unroll
        for (int mt = 0; mt < 4; ++mt)
            #pragma unroll
            for (int nt = 0; nt < 4; ++nt)
                acc[mt][nt] = __builtin_amdgcn_mfma_f32_16x16x32_f16(af[mt], bfr[nt], acc[mt][nt], 0, 0, 0);
        // prefetch layer-1 s=0 A-frags (stays in flight across BAR)
        const unsigned short* wn = whs + (b * 4 + 0) * H * H;
        #pragma unroll
        for (int mt = 0; mt < 4; ++mt)
            af0[mt] = __builtin_bit_cast(half8,
                *(const ushort8_t*)&wn[(mh + mt * 16 + c) * H + q * 8]);
    }
    BAR();
    // ---- epilogue layer 0 ----
    #pragma unroll
    for (int mt = 0; mt < 4; ++mt) {
        int f0 = mh + mt * 16 + q * 4;
        floatx4 bi4 = *(const floatx4*)&binit[(b * LNUM + 0) * H + f0];
        floatx4 a4  = *(const floatx4*)&talpha[0 * H + f0];
        #pragma unroll
        for (int nt = 0; nt < 4; ++nt) {
            int pt = nt * 16 + c;
            floatx4 v = acc[mt][nt];
            #pragma unroll
            for (int r = 0; r < 4; ++r) {
                float e  = __builtin_amdgcn_exp2f(v[r] + bi4[r]);   // 2log2e*S*(Wx+b)
                float rc = __builtin_amdgcn_rcpf(e + 1.0f);
                v[r] = __builtin_fmaf(-2.0f * a4[r], rc, a4[r]);    // a*tanh
            }
            uint2v u;
            u.x = __builtin_bit_cast(unsigned int, __builtin_amdgcn_cvt_pkrtz(v[0], v[1]));
            u.y = __builtin_bit_cast(unsigned int, __builtin_amdgcn_cvt_pkrtz(v[2], v[3]));
            *(uint2v*)&xs[pt * XROW + f0] = u;
        }
    }

    // ================= layers 1..4 (folded Wh) and 5 (Wf) =================
    for (int l = 1; l <= 5; ++l) {
        const unsigned short* wl = (l < 5) ? whs + (b * 4 + (l - 1)) * H * H : wft;
        #pragma unroll
        for (int mt = 0; mt < 4; ++mt)
            #pragma unroll
            for (int nt = 0; nt < 4; ++nt)
                acc[mt][nt] = (floatx4){0.f, 0.f, 0.f, 0.f};
        BAR();                                    // prev epilogue writes visible
        #pragma unroll
        for (int s = 0; s < 4; ++s) {
            half8 af[4], bfr[4];
            #pragma unroll
            for (int mt = 0; mt < 4; ++mt)
                af[mt] = (s == 0) ? af0[mt] : __builtin_bit_cast(half8,
                    *(const ushort8_t*)&wl[(mh + mt * 16 + c) * H + s * 32 + q * 8]);
            #pragma unroll
            for (int nt = 0; nt < 4; ++nt)
                bfr[nt] = __builtin_bit_cast(half8,
                    *(const ushort8_t*)&xs[(nt * 16 + c) * XROW + s * 32 + q * 8]);
            #pragma unroll
            for (int mt = 0; mt < 4; ++mt)
                #pragma unroll
                for (int nt = 0; nt < 4; ++nt)
                    acc[mt][nt] = __builtin_amdgcn_mfma_f32_16x16x32_f16(af[mt], bfr[nt], acc[mt][nt], 0, 0, 0);
        }
        if (l < 5) {                              // prefetch next layer's s=0 A-frags
            const unsigned short* wn = (l < 4) ? whs + (b * 4 + l) * H * H : wft;
            #pragma unroll
            for (int mt = 0; mt < 4; ++mt)
                af0[mt] = __builtin_bit_cast(half8,
                    *(const ushort8_t*)&wn[(mh + mt * 16 + c) * H + q * 8]);
        }
        BAR();                                    // all xs reads done before overwrite

        if (l < 5) {
            #pragma unroll
            for (int mt = 0; mt < 4; ++mt) {
                int f0 = mh + mt * 16 + q * 4;
                floatx4 bi4 = *(const floatx4*)&binit[(b * LNUM + l) * H + f0];
                floatx4 a4  = *(const floatx4*)&talpha[l * H + f0];
                #pragma unroll
                for (int nt = 0; nt < 4; ++nt) {
                    int pt = nt * 16 + c;
                    floatx4 v = acc[mt][nt];
                    #pragma unroll
                    for (int r = 0; r < 4; ++r) {
                        float e  = __builtin_amdgcn_exp2f(v[r] + bi4[r]);
                        float rc = __builtin_amdgcn_rcpf(e + 1.0f);
                        v[r] = __builtin_fmaf(-2.0f * a4[r], rc, a4[r]);
                    }
                    uint2v u;
                    u.x = __builtin_bit_cast(unsigned int, __builtin_amdgcn_cvt_pkrtz(v[0], v[1]));
                    u.y = __builtin_bit_cast(unsigned int, __builtin_amdgcn_cvt_pkrtz(v[2], v[3]));
                    *(uint2v*)&xs[pt * XROW + f0] = u;
                }
            }
        } else {
            #pragma unroll
            for (int mt = 0; mt < 4; ++mt) {
                int f0 = mh + mt * 16 + q * 4;
                floatx4 f4 = *(const floatx4*)&tbf[f0];
                #pragma unroll
                for (int nt = 0; nt < 4; ++nt) {
                    int pt = nt * 16 + c;
                    floatx4 v = acc[mt][nt];
                    uint2v u;
                    u.x = __builtin_bit_cast(unsigned int, __builtin_amdgcn_cvt_pkrtz(v[0] + f4[0], v[1] + f4[1]));
                    u.y = __builtin_bit_cast(unsigned int, __builtin_amdgcn_cvt_pkrtz(v[2] + f4[2], v[3] + f4[3]));
                    *(uint2v*)&xs[pt * XROW + f0] = u;
                }
            }
        }
    }
    BAR();                                        // YL ready in xs

    // ---- einsum: out[b,pt,o] = sum_h ZL[o,h] * YL[pt,h]; A=ZL (m=o), B=YL (n=pt) ----
    {
        floatx4 oacc[2] = {(floatx4){0,0,0,0}, (floatx4){0,0,0,0}};
        const unsigned short* zl = ZLws + b * 16 * H;
        #pragma unroll
        for (int s = 0; s < 4; ++s) {
            half8 af = __builtin_bit_cast(half8,
                *(const ushort8_t*)&zl[c * H + s * 32 + q * 8]);
            #pragma unroll
            for (int nt = 0; nt < 2; ++nt) {
                half8 bfr = __builtin_bit_cast(half8,
                    *(const ushort8_t*)&xs[(w * 32 + nt * 16 + c) * XROW + s * 32 + q * 8]);
                oacc[nt] = __builtin_amdgcn_mfma_f32_16x16x32_f16(af, bfr, oacc[nt], 0, 0, 0);
            }
        }
        #pragma unroll
        for (int nt = 0; nt < 2; ++nt) {
            int pt = n0 + w * 32 + nt * 16 + c;
            if (pt < NPTS) {
                float* op = out + ((size_t)b * NPTS + pt) * ONUM;
                if (q == 0) {
                    op[0] = oacc[nt][0]; op[1] = oacc[nt][1];
                    op[2] = oacc[nt][2]; op[3] = oacc[nt][3];
                } else if (q == 1) {
                    op[4] = oacc[nt][0];
                }
            }
        }
    }
}

extern "C" void kernel_launch(void* const* d_in, const int* in_sizes, int n_in,
                              void* d_out, int out_size, void* d_ws, size_t ws_size,
                              hipStream_t stream) {
    const float* coords       = (const float*)d_in[0];
    const float* params       = (const float*)d_in[1];
    const float* branch_W0    = (const float*)d_in[2];
    const float* branch_b0    = (const float*)d_in[3];
    const float* branch_Wh    = (const float*)d_in[4];
    const float* branch_bh    = (const float*)d_in[5];
    const float* branch_alpha = (const float*)d_in[6];
    const float* branch_Wf    = (const float*)d_in[7];
    const float* branch_bf    = (const float*)d_in[8];
    const float* trunk_W0     = (const float*)d_in[9];
    const float* trunk_b0     = (const float*)d_in[10];
    const float* trunk_Wh     = (const float*)d_in[11];
    const float* trunk_bh     = (const float*)d_in[12];
    const float* trunk_alpha  = (const float*)d_in[13];
    const float* trunk_Wf     = (const float*)d_in[14];
    const float* trunk_bf     = (const float*)d_in[15];
    float* out = (float*)d_out;

    // workspace layout (256B-aligned offsets)
    char* ws = (char*)d_ws;
    float*          Sws   = (float*)(ws + 0);                 // 16*5*128 f32   = 40960
    float*          binit = (float*)(ws + 40960);             // 16*5*128 f32   = 40960
    unsigned short* ZLws  = (unsigned short*)(ws + 81920);    // 16*16*128 f16  = 65536
    unsigned short* wft   = (unsigned short*)(ws + 147456);   // 128*128 f16    = 32768
    unsigned short* w0s   = (unsigned short*)(ws + 180224);   // 16*128*32 f16  = 131072
    unsigned short* whs   = (unsigned short*)(ws + 311296);   // 16*4*128*128   = 2097152
    // end: 2408448 B

    branch_kernel<<<dim3(BATCH), 256, 0, stream>>>(params, branch_W0, branch_b0,
                                                   branch_Wh, branch_bh, branch_alpha,
                                                   branch_Wf, branch_bf, Sws, ZLws);
    fold_kernel<<<dim3(BATCH, 6), 256, 0, stream>>>(trunk_W0, trunk_b0, trunk_Wh, trunk_bh,
                                                    trunk_Wf, Sws, w0s, whs, wft, binit);
    trunk_kernel<<<dim3((NPTS + TP - 1) / TP, BATCH), 128, 0, stream>>>(
        coords, trunk_alpha, trunk_bf, wft, w0s, whs, binit, ZLws, out);
}

// Round 6
// 401.927 us; speedup vs baseline: 1.2043x; 1.2043x over previous
//
#include <hip/hip_runtime.h>
#include <math.h>

#define H      128
#define LNUM   5
#define ONUM   5
#define BATCH  16
#define NPTS   50000
#define TP     64       // points per trunk block (2 waves)
#define XROW   152      // halfs per xs row: 128+24 pad

#define K2LOG2E 2.8853900817779268f   // 2*log2(e): tanh arg -> exp2 arg

typedef _Float16      half8    __attribute__((ext_vector_type(8)));
typedef float         floatx4  __attribute__((ext_vector_type(4)));
typedef unsigned int  uint2v   __attribute__((ext_vector_type(2)));
typedef unsigned int  uint4v   __attribute__((ext_vector_type(4)));
typedef unsigned short ushort8_t __attribute__((ext_vector_type(8)));

// LDS-only barrier: lgkmcnt drain + s_barrier. Cross-wave hazards here are all LDS;
// leaves global (weight) loads in flight across the barrier (no vmcnt(0) stall).
#define BAR() asm volatile("s_waitcnt lgkmcnt(0)\ns_barrier" ::: "memory")

static __device__ __forceinline__ unsigned short f2h(float f) {
    _Float16 h = (_Float16)f;                       // v_cvt_f16_f32 (RNE)
    return __builtin_bit_cast(unsigned short, h);
}

// ============ branch MLP: one block per batch; outputs S (cumsum), ZL ============
__global__ __launch_bounds__(256)
void branch_kernel(const float* __restrict__ params,
                   const float* __restrict__ bW0, const float* __restrict__ bb0,
                   const float* __restrict__ bWh, const float* __restrict__ bbh,
                   const float* __restrict__ balpha,
                   const float* __restrict__ bWf, const float* __restrict__ bbf,
                   float* __restrict__ Sws, unsigned short* __restrict__ ZLws) {
    int b = blockIdx.x, t = threadIdx.x;
    __shared__ float hbuf[H];
    __shared__ float pbuf[8];
    if (t < 8) pbuf[t] = params[b * 8 + t];
    __syncthreads();

    float scum = 0.0f;
    if (t < H) {
        float acc = bb0[t];
        for (int k = 0; k < 8; ++k) acc += pbuf[k] * bW0[k * H + t];
        float h = balpha[t] * tanhf(acc);
        hbuf[t] = h;
        scum = h;
        Sws[(b * LNUM + 0) * H + t] = scum;
    }
    for (int i = 1; i < LNUM; ++i) {
        __syncthreads();
        float hn = 0.0f;
        if (t < H) {
            const float* Wl = bWh + (i - 1) * H * H;
            float a2 = bbh[(i - 1) * H + t];
            for (int k = 0; k < H; ++k) a2 += hbuf[k] * Wl[k * H + t];
            hn = balpha[i * H + t] * tanhf(a2);
        }
        __syncthreads();
        if (t < H) {
            hbuf[t] = hn;
            scum += hn;
            Sws[(b * LNUM + i) * H + t] = scum;
        }
    }
    __syncthreads();
    // ZL[b][o][h], o=5..15 zero rows
    for (int idx = t; idx < 16 * H; idx += 256) {
        int o = idx >> 7, hh = idx & 127;
        float z = 0.0f;
        if (o < ONUM) {
            z = bbf[o * H + hh];
            for (int k = 0; k < H; ++k) z += hbuf[k] * bWf[k * (H * ONUM) + o * H + hh];
        }
        ZLws[b * 16 * H + idx] = f2h(z);
    }
}

// ============ massively-parallel weight fold: grid (16, 6) ============
// whs[b][l-1][f][k] = 2log2e*S_l[f] * Wh[l-1][k][f] * alpha_{l-1}[k]   (alpha folded into k)
// w0s[b][f][k]      = 2log2e*S_0[f] * W0[k][f]  (K padded to 32)
// wft[f][k]         = Wf[k][f] * alpha_4[k]      (batch-independent)
__global__ __launch_bounds__(256)
void fold_kernel(const float* __restrict__ tW0, const float* __restrict__ tb0,
                 const float* __restrict__ tWh, const float* __restrict__ tbh,
                 const float* __restrict__ tWf, const float* __restrict__ talpha,
                 const float* __restrict__ Sws,
                 unsigned short* __restrict__ w0s, unsigned short* __restrict__ whs,
                 unsigned short* __restrict__ wft, float* __restrict__ binit) {
    int b = blockIdx.x, l = blockIdx.y, t = threadIdx.x;
    if (l == 5) {
        if (b == 0) {
            for (int i = t; i < H * H; i += 256) {
                int k = i >> 7, f = i & 127;          // src coalesced
                wft[f * H + k] = f2h(tWf[i] * talpha[4 * H + k]);
            }
        }
        return;
    }
    const float* Srow = Sws + (b * LNUM + l) * H;
    if (l == 0) {
        for (int i = t; i < H * 32; i += 256) {
            int f = i >> 5, k = i & 31;
            float v = (k < 3) ? K2LOG2E * Srow[f] * tW0[k * H + f] : 0.0f;
            w0s[b * H * 32 + i] = f2h(v);
        }
        if (t < H) binit[(b * LNUM + 0) * H + t] = K2LOG2E * Srow[t] * tb0[t];
    } else {
        const float* Wsrc = tWh + (l - 1) * H * H;
        unsigned short* dst = whs + (b * 4 + (l - 1)) * H * H;
        for (int i = t; i < H * H; i += 256) {
            int k = i >> 7, f = i & 127;              // src coalesced
            dst[f * H + k] = f2h(K2LOG2E * Srow[f] * Wsrc[i] * talpha[(l - 1) * H + k]);
        }
        if (t < H) binit[(b * LNUM + l) * H + t] = K2LOG2E * Srow[t] * tbh[(l - 1) * H + t];
    }
}

// ============ trunk: 64 points/block (2 waves), fp16 MFMA, feature-major D ============
// acc[4][4] = 64 AGPR; unified VGPR+AGPR budget at 3 waves/EU = 170 -> fits (~148).
// NEVER request 4 waves/EU here: budget 128 forces a full scratch spill (R3/R5).
__global__ __launch_bounds__(128, 3)
void trunk_kernel(const float* __restrict__ coords,
                  const float* __restrict__ tbf,
                  const unsigned short* __restrict__ wft,
                  const unsigned short* __restrict__ w0s,
                  const unsigned short* __restrict__ whs,
                  const float* __restrict__ binit,
                  const unsigned short* __restrict__ ZLws,
                  float* __restrict__ out) {
    const int b    = blockIdx.y;
    const int n0   = blockIdx.x * TP;
    const int tid  = threadIdx.x;
    const int lane = tid & 63;
    const int w    = tid >> 6;        // wave 0/1
    const int q    = lane >> 4;       // quad 0..3
    const int c    = lane & 15;
    const int mh   = w * 64;          // wave's feature half (M); both waves cover all 64 points

    __shared__ unsigned short xs[TP * XROW];   // 19456 B

    // ---- stage coords into xs[p][0..31] (fp16, zero-padded K) ----
    int valid = NPTS - n0; if (valid > TP) valid = TP;
    {
        int p = tid >> 1, hh = tid & 1;
        if (hh == 0) {
            float c0 = 0.f, c1 = 0.f, c2 = 0.f;
            if (p < valid) {
                const float* cp = coords + ((size_t)b * NPTS + n0 + p) * 3;
                c0 = cp[0]; c1 = cp[1]; c2 = cp[2];
            }
            uint4v z;
            z.x = __builtin_bit_cast(unsigned int, __builtin_amdgcn_cvt_pkrtz(c0, c1));
            z.y = __builtin_bit_cast(unsigned int, __builtin_amdgcn_cvt_pkrtz(c2, 0.0f));
            z.z = 0; z.w = 0;
            *(uint4v*)&xs[p * XROW + 0] = z;                 // k 0..7
            uint4v zz = {0, 0, 0, 0};
            *(uint4v*)&xs[p * XROW + 8] = zz;                // k 8..15
        } else {
            uint4v zz = {0, 0, 0, 0};
            *(uint4v*)&xs[p * XROW + 16] = zz;               // k 16..31
            *(uint4v*)&xs[p * XROW + 24] = zz;
        }
    }
    BAR();

    floatx4 acc[4][4];
    half8 af0[4];                                   // cross-barrier s=0 A-frag prefetch

    // ================= layer 0: coords (K=32, folded W0) =================
    #pragma unroll
    for (int mt = 0; mt < 4; ++mt)
        #pragma unroll
        for (int nt = 0; nt < 4; ++nt)
            acc[mt][nt] = (floatx4){0.f, 0.f, 0.f, 0.f};
    {
        const unsigned short* w0b = w0s + b * H * 32;
        half8 af[4], bfr[4];
        #pragma unroll
        for (int mt = 0; mt < 4; ++mt)
            af[mt] = __builtin_bit_cast(half8,
                *(const ushort8_t*)&w0b[(mh + mt * 16 + c) * 32 + q * 8]);
        #pragma unroll
        for (int nt = 0; nt < 4; ++nt)
            bfr[nt] = __builtin_bit_cast(half8,
                *(const ushort8_t*)&xs[(nt * 16 + c) * XROW + q * 8]);
        #pragma unroll
        for (int mt = 0; mt < 4; ++mt)
            #pragma unroll
            for (int nt = 0; nt < 4; ++nt)
                acc[mt][nt] = __builtin_amdgcn_mfma_f32_16x16x32_f16(af[mt], bfr[nt], acc[mt][nt], 0, 0, 0);
        // prefetch layer-1 s=0 A-frags (stays in flight across BAR)
        const unsigned short* wn = whs + (b * 4 + 0) * H * H;
        #pragma unroll
        for (int mt = 0; mt < 4; ++mt)
            af0[mt] = __builtin_bit_cast(half8,
                *(const ushort8_t*)&wn[(mh + mt * 16 + c) * H + q * 8]);
    }
    BAR();
    // ---- epilogue layer 0: write tanh(acc + binit); alpha folded into next W ----
    #pragma unroll
    for (int mt = 0; mt < 4; ++mt) {
        int f0 = mh + mt * 16 + q * 4;
        floatx4 bi4 = *(const floatx4*)&binit[(b * LNUM + 0) * H + f0];
        #pragma unroll
        for (int nt = 0; nt < 4; ++nt) {
            int pt = nt * 16 + c;
            floatx4 v = acc[mt][nt];
            #pragma unroll
            for (int r = 0; r < 4; ++r) {
                float e  = __builtin_amdgcn_exp2f(v[r] + bi4[r]);   // 2log2e*S*(Wx+b)
                float rc = __builtin_amdgcn_rcpf(e + 1.0f);
                v[r] = __builtin_fmaf(-2.0f, rc, 1.0f);             // tanh
            }
            uint2v u;
            u.x = __builtin_bit_cast(unsigned int, __builtin_amdgcn_cvt_pkrtz(v[0], v[1]));
            u.y = __builtin_bit_cast(unsigned int, __builtin_amdgcn_cvt_pkrtz(v[2], v[3]));
            *(uint2v*)&xs[pt * XROW + f0] = u;
        }
    }

    // ================= layers 1..4 (folded Wh) and 5 (Wf) =================
    for (int l = 1; l <= 5; ++l) {
        const unsigned short* wl = (l < 5) ? whs + (b * 4 + (l - 1)) * H * H : wft;
        #pragma unroll
        for (int mt = 0; mt < 4; ++mt)
            #pragma unroll
            for (int nt = 0; nt < 4; ++nt)
                acc[mt][nt] = (floatx4){0.f, 0.f, 0.f, 0.f};
        BAR();                                    // prev epilogue writes visible
        #pragma unroll
        for (int s = 0; s < 4; ++s) {
            half8 af[4], bfr[4];
            #pragma unroll
            for (int mt = 0; mt < 4; ++mt)
                af[mt] = (s == 0) ? af0[mt] : __builtin_bit_cast(half8,
                    *(const ushort8_t*)&wl[(mh + mt * 16 + c) * H + s * 32 + q * 8]);
            #pragma unroll
            for (int nt = 0; nt < 4; ++nt)
                bfr[nt] = __builtin_bit_cast(half8,
                    *(const ushort8_t*)&xs[(nt * 16 + c) * XROW + s * 32 + q * 8]);
            #pragma unroll
            for (int mt = 0; mt < 4; ++mt)
                #pragma unroll
                for (int nt = 0; nt < 4; ++nt)
                    acc[mt][nt] = __builtin_amdgcn_mfma_f32_16x16x32_f16(af[mt], bfr[nt], acc[mt][nt], 0, 0, 0);
        }
        if (l < 5) {                              // prefetch next layer's s=0 A-frags
            const unsigned short* wn = (l < 4) ? whs + (b * 4 + l) * H * H : wft;
            #pragma unroll
            for (int mt = 0; mt < 4; ++mt)
                af0[mt] = __builtin_bit_cast(half8,
                    *(const ushort8_t*)&wn[(mh + mt * 16 + c) * H + q * 8]);
        }
        BAR();                                    // all xs reads done before overwrite

        if (l < 5) {
            #pragma unroll
            for (int mt = 0; mt < 4; ++mt) {
                int f0 = mh + mt * 16 + q * 4;
                floatx4 bi4 = *(const floatx4*)&binit[(b * LNUM + l) * H + f0];
                #pragma unroll
                for (int nt = 0; nt < 4; ++nt) {
                    int pt = nt * 16 + c;
                    floatx4 v = acc[mt][nt];
                    #pragma unroll
                    for (int r = 0; r < 4; ++r) {
                        float e  = __builtin_amdgcn_exp2f(v[r] + bi4[r]);
                        float rc = __builtin_amdgcn_rcpf(e + 1.0f);
                        v[r] = __builtin_fmaf(-2.0f, rc, 1.0f);
                    }
                    uint2v u;
                    u.x = __builtin_bit_cast(unsigned int, __builtin_amdgcn_cvt_pkrtz(v[0], v[1]));
                    u.y = __builtin_bit_cast(unsigned int, __builtin_amdgcn_cvt_pkrtz(v[2], v[3]));
                    *(uint2v*)&xs[pt * XROW + f0] = u;
                }
            }
        } else {
            #pragma unroll
            for (int mt = 0; mt < 4; ++mt) {
                int f0 = mh + mt * 16 + q * 4;
                floatx4 f4 = *(const floatx4*)&tbf[f0];
                #pragma unroll
                for (int nt = 0; nt < 4; ++nt) {
                    int pt = nt * 16 + c;
                    floatx4 v = acc[mt][nt];
                    uint2v u;
                    u.x = __builtin_bit_cast(unsigned int, __builtin_amdgcn_cvt_pkrtz(v[0] + f4[0], v[1] + f4[1]));
                    u.y = __builtin_bit_cast(unsigned int, __builtin_amdgcn_cvt_pkrtz(v[2] + f4[2], v[3] + f4[3]));
                    *(uint2v*)&xs[pt * XROW + f0] = u;
                }
            }
        }
    }
    BAR();                                        // YL ready in xs

    // ---- einsum: out[b,pt,o] = sum_h ZL[o,h] * YL[pt,h]; A=ZL (m=o), B=YL (n=pt) ----
    {
        floatx4 oacc[2] = {(floatx4){0,0,0,0}, (floatx4){0,0,0,0}};
        const unsigned short* zl = ZLws + b * 16 * H;
        #pragma unroll
        for (int s = 0; s < 4; ++s) {
            half8 af = __builtin_bit_cast(half8,
                *(const ushort8_t*)&zl[c * H + s * 32 + q * 8]);
            #pragma unroll
            for (int nt = 0; nt < 2; ++nt) {
                half8 bfr = __builtin_bit_cast(half8,
                    *(const ushort8_t*)&xs[(w * 32 + nt * 16 + c) * XROW + s * 32 + q * 8]);
                oacc[nt] = __builtin_amdgcn_mfma_f32_16x16x32_f16(af, bfr, oacc[nt], 0, 0, 0);
            }
        }
        #pragma unroll
        for (int nt = 0; nt < 2; ++nt) {
            int pt = n0 + w * 32 + nt * 16 + c;
            if (pt < NPTS) {
                float* op = out + ((size_t)b * NPTS + pt) * ONUM;
                if (q == 0) {
                    op[0] = oacc[nt][0]; op[1] = oacc[nt][1];
                    op[2] = oacc[nt][2]; op[3] = oacc[nt][3];
                } else if (q == 1) {
                    op[4] = oacc[nt][0];
                }
            }
        }
    }
}

extern "C" void kernel_launch(void* const* d_in, const int* in_sizes, int n_in,
                              void* d_out, int out_size, void* d_ws, size_t ws_size,
                              hipStream_t stream) {
    const float* coords       = (const float*)d_in[0];
    const float* params       = (const float*)d_in[1];
    const float* branch_W0    = (const float*)d_in[2];
    const float* branch_b0    = (const float*)d_in[3];
    const float* branch_Wh    = (const float*)d_in[4];
    const float* branch_bh    = (const float*)d_in[5];
    const float* branch_alpha = (const float*)d_in[6];
    const float* branch_Wf    = (const float*)d_in[7];
    const float* branch_bf    = (const float*)d_in[8];
    const float* trunk_W0     = (const float*)d_in[9];
    const float* trunk_b0     = (const float*)d_in[10];
    const float* trunk_Wh     = (const float*)d_in[11];
    const float* trunk_bh     = (const float*)d_in[12];
    const float* trunk_alpha  = (const float*)d_in[13];
    const float* trunk_Wf     = (const float*)d_in[14];
    const float* trunk_bf     = (const float*)d_in[15];
    float* out = (float*)d_out;

    // workspace layout (256B-aligned offsets)
    char* ws = (char*)d_ws;
    float*          Sws   = (float*)(ws + 0);                 // 16*5*128 f32   = 40960
    float*          binit = (float*)(ws + 40960);             // 16*5*128 f32   = 40960
    unsigned short* ZLws  = (unsigned short*)(ws + 81920);    // 16*16*128 f16  = 65536
    unsigned short* wft   = (unsigned short*)(ws + 147456);   // 128*128 f16    = 32768
    unsigned short* w0s   = (unsigned short*)(ws + 180224);   // 16*128*32 f16  = 131072
    unsigned short* whs   = (unsigned short*)(ws + 311296);   // 16*4*128*128   = 2097152
    // end: 2408448 B

    branch_kernel<<<dim3(BATCH), 256, 0, stream>>>(params, branch_W0, branch_b0,
                                                   branch_Wh, branch_bh, branch_alpha,
                                                   branch_Wf, branch_bf, Sws, ZLws);
    fold_kernel<<<dim3(BATCH, 6), 256, 0, stream>>>(trunk_W0, trunk_b0, trunk_Wh, trunk_bh,
                                                    trunk_Wf, trunk_alpha, Sws,
                                                    w0s, whs, wft, binit);
    trunk_kernel<<<dim3((NPTS + TP - 1) / TP, BATCH), 128, 0, stream>>>(
        coords, trunk_bf, wft, w0s, whs, binit, ZLws, out);
}